// Round 1
// baseline (1272.204 us; speedup 1.0000x reference)
//
#include <hip/hip_runtime.h>

#define CIN   64
#define COUT  128
#define HH    512
#define WW    512
#define HW    (HH*WW)          // 262144

typedef __attribute__((ext_vector_type(8))) short  short8;   // 8 bf16
typedef __attribute__((ext_vector_type(4))) float  floatx4;

// ---------------- helpers ----------------

__device__ __forceinline__ unsigned short f2bf(float f) {
    unsigned u = __float_as_uint(f);
    u += 0x7fffu + ((u >> 16) & 1u);     // RNE
    return (unsigned short)(u >> 16);
}

// LDS row swizzle: breaks the stride-8 bank pattern of the bitrev gather
__device__ __forceinline__ int ph(int i) { return i ^ ((i >> 6) & 7); }

__device__ __forceinline__ int bitrev9(int i) { return (int)(__brev((unsigned)i) >> 23); }

// ---------------- prep kernels ----------------

__global__ void k_cvt_x(const float4* __restrict__ x4, ushort4* __restrict__ xb4) {
    int i = blockIdx.x * 256 + threadIdx.x;          // 4,194,304 total
    float4 v = x4[i];
    ushort4 o;
    o.x = f2bf(v.x); o.y = f2bf(v.y); o.z = f2bf(v.z); o.w = f2bf(v.w);
    xb4[i] = o;
}

// wr[tap][co][ci] <- conv_w[co][ci][dy][dx],  tap = dy*3+dx
__global__ void k_cvt_w(const float* __restrict__ w, unsigned short* __restrict__ wr) {
    int i = blockIdx.x * 256 + threadIdx.x;
    if (i < 9 * COUT * CIN) {
        int ci  = i & 63;
        int co  = (i >> 6) & 127;
        int tap = i >> 13;
        wr[i] = f2bf(w[(co * CIN + ci) * 9 + tap]);
    }
}

// ---------------- conv: implicit GEMM, bf16 MFMA ----------------
// Block: 128 pixels (one row h, w0..w0+127) x all 128 out-channels. K = 9 taps x 64 ci.
// 4 waves in 2x2; each wave 64x64 via 4x4 of 16x16x32 MFMA.

__global__ __launch_bounds__(256) void k_conv(
        const unsigned short* __restrict__ xb,   // bf16 x [ci][h][w]
        const unsigned short* __restrict__ wr,   // bf16 [tap][co][ci]
        const float* __restrict__ bias,
        float* __restrict__ y)                   // fp32 [co][h][w]
{
    __shared__ __align__(16) unsigned short As[3][130][72];  // [dy][wpos][ci]
    __shared__ __align__(16) unsigned short Bs[128][72];     // [co][ci]

    int b  = blockIdx.x;
    int h  = b >> 2;
    int w0 = (b & 3) << 7;
    int t  = threadIdx.x;
    int lane = t & 63, wv = t >> 6;
    int wm = wv & 1, wn = wv >> 1;
    int l15 = lane & 15, quad = lane >> 4;

    // stage A once: 3 rows x 64 ci x 130 width (halo +-1), zero-fill OOB
    for (int idx = t; idx < 3 * 64 * 130; idx += 256) {
        int dy  = idx / (64 * 130);
        int rem = idx - dy * (64 * 130);
        int ci  = rem / 130;
        int p   = rem - ci * 130;
        int hp  = h + dy - 1;
        int wq  = w0 - 1 + p;
        unsigned short v = 0;
        if ((unsigned)hp < 512u && (unsigned)wq < 512u)
            v = xb[ci * HW + hp * 512 + wq];
        As[dy][p][ci] = v;
    }

    floatx4 acc[4][4];
#pragma unroll
    for (int mt = 0; mt < 4; ++mt)
#pragma unroll
        for (int nt = 0; nt < 4; ++nt) {
            floatx4 z = {0.f, 0.f, 0.f, 0.f};
            acc[mt][nt] = z;
        }

    for (int tap = 0; tap < 9; ++tap) {
        int dy = tap / 3, dx = tap - dy * 3;
        __syncthreads();
        for (int i = t; i < COUT * CIN; i += 256) {
            Bs[i >> 6][i & 63] = wr[tap * (COUT * CIN) + i];
        }
        __syncthreads();
#pragma unroll
        for (int kc = 0; kc < 2; ++kc) {
            int c0 = kc * 32 + quad * 8;
            short8 afr[4], bfr[4];
#pragma unroll
            for (int mt = 0; mt < 4; ++mt) {
                int row = wm * 64 + mt * 16 + l15 + dx;
                afr[mt] = *(const short8*)&As[dy][row][c0];
            }
#pragma unroll
            for (int nt = 0; nt < 4; ++nt) {
                int co = wn * 64 + nt * 16 + l15;
                bfr[nt] = *(const short8*)&Bs[co][c0];
            }
#pragma unroll
            for (int mt = 0; mt < 4; ++mt)
#pragma unroll
                for (int nt = 0; nt < 4; ++nt)
                    acc[mt][nt] = __builtin_amdgcn_mfma_f32_16x16x32_bf16(
                        afr[mt], bfr[nt], acc[mt][nt], 0, 0, 0);
        }
    }

    // epilogue: D(row m = quad*4+r, col n = l15) per 16x16 tile
#pragma unroll
    for (int nt = 0; nt < 4; ++nt) {
        int co = wn * 64 + nt * 16 + l15;
        float bv = bias[co];
#pragma unroll
        for (int mt = 0; mt < 4; ++mt) {
#pragma unroll
            for (int r = 0; r < 4; ++r) {
                int m = wm * 64 + mt * 16 + quad * 4 + r;
                y[co * HW + h * 512 + w0 + m] = acc[mt][nt][r] + bv;
            }
        }
    }
}

// ---------------- FFT pieces ----------------
// LDS layout: s[idx 0..511 -> swizzled row ph(idx)][lane c 0..15], stride 17.
// 256 threads = 16 independent FFTs x 16 workers; worker does 16 butterflies/stage.

#define LSTR 17

__device__ __forceinline__ void build_tw(float* twr, float* twi, int t) {
    if (t < 256) {
        float ang = -6.283185307179586f * (float)t / 512.0f;
        float s, c;
        __sincosf(ang, &s, &c);
        twr[t] = c; twi[t] = s;
    }
}

// DIF: natural in -> bitrev out. dir = +1 forward, -1 (unscaled) inverse.
__device__ void fft_dif(float (*sR)[LSTR], float (*sI)[LSTR],
                        const float* twr, const float* twi,
                        int c, int w, float dir) {
    for (int s = 0; s < 9; ++s) {
        int mh = 256 >> s;
        int lg = 8 - s;
        __syncthreads();
        for (int b = 0; b < 16; ++b) {
            int j  = w + 16 * b;
            int p  = j & (mh - 1);
            int i0 = ((j >> lg) << (lg + 1)) + p;
            int i1 = i0 + mh;
            int r0 = ph(i0), r1 = ph(i1);
            float ar = sR[r0][c], ai = sI[r0][c];
            float br = sR[r1][c], bi = sI[r1][c];
            float tr = ar - br, ti = ai - bi;
            sR[r0][c] = ar + br; sI[r0][c] = ai + bi;
            int tx = p << s;
            float wr_ = twr[tx], wi_ = dir * twi[tx];
            sR[r1][c] = tr * wr_ - ti * wi_;
            sI[r1][c] = tr * wi_ + ti * wr_;
        }
    }
    __syncthreads();
}

// DIT inverse (unscaled): bitrev in -> natural out.
__device__ void fft_dit_inv(float (*sR)[LSTR], float (*sI)[LSTR],
                            const float* twr, const float* twi, int c, int w) {
    for (int s = 0; s < 9; ++s) {
        int mh = 1 << s;
        __syncthreads();
        for (int b = 0; b < 16; ++b) {
            int j  = w + 16 * b;
            int p  = j & (mh - 1);
            int i0 = ((j >> s) << (s + 1)) + p;
            int i1 = i0 + mh;
            int r0 = ph(i0), r1 = ph(i1);
            int tx = p << (8 - s);
            float wr_ = twr[tx], wi_ = -twi[tx];     // conj -> e^{+i}
            float br = sR[r1][c], bi = sI[r1][c];
            float tr = br * wr_ - bi * wi_;
            float ti = br * wi_ + bi * wr_;
            float ar = sR[r0][c], ai = sI[r0][c];
            sR[r0][c] = ar + tr; sI[r0][c] = ai + ti;
            sR[r1][c] = ar - tr; sI[r1][c] = ai - ti;
        }
    }
    __syncthreads();
}

// F2: forward FFT along W for 16 rows of one channel; output natural order.
__global__ __launch_bounds__(256) void k_fft_rows_fwd(float* __restrict__ yRe,
                                                      float* __restrict__ yIm) {
    __shared__ float sR[512][LSTR], sI[512][LSTR];
    __shared__ float twr[256], twi[256];
    int t = threadIdx.x;
    build_tw(twr, twi, t);
    int co = blockIdx.x >> 5, r0 = (blockIdx.x & 31) << 4;
    size_t base = (size_t)co * HW + (size_t)r0 * 512;

    for (int it = 0; it < 32; ++it) {
        int n = t + 256 * it;
        int rr = n >> 9, j = n & 511;
        sR[ph(j)][rr] = yRe[base + rr * 512 + j];
        sI[ph(j)][rr] = 0.f;
    }
    int c = t & 15, w = t >> 4;
    fft_dif(sR, sI, twr, twi, c, w, 1.0f);
    for (int it = 0; it < 32; ++it) {
        int n = t + 256 * it;
        int rr = n >> 9, k = n & 511;
        int src = ph(bitrev9(k));
        yRe[base + rr * 512 + k] = sR[src][rr];
        yIm[base + rr * 512 + k] = sI[src][rr];
    }
}

// F3: 16 columns: fwd FFT along H (DIF->bitrev), mask*1/N^2 at bitrev rows,
// inverse DIT (bitrev->natural). No physical reordering needed.
__global__ __launch_bounds__(256) void k_fft_cols(float* __restrict__ bRe,
                                                  float* __restrict__ bIm,
                                                  const float* __restrict__ mask) {
    __shared__ float sR[512][LSTR], sI[512][LSTR];
    __shared__ float twr[256], twi[256];
    int t = threadIdx.x;
    build_tw(twr, twi, t);
    int co = blockIdx.x >> 5, c0 = (blockIdx.x & 31) << 4;
    size_t base = (size_t)co * HW + c0;
    int c = t & 15, w = t >> 4;

    for (int it = 0; it < 32; ++it) {
        int i = w + 16 * it;
        sR[ph(i)][c] = bRe[base + (size_t)i * 512 + c];
        sI[ph(i)][c] = bIm[base + (size_t)i * 512 + c];
    }
    fft_dif(sR, sI, twr, twi, c, w, 1.0f);

    const float scale = 1.0f / (512.0f * 512.0f);
    for (int it = 0; it < 32; ++it) {
        int i = w + 16 * it;
        int kr = bitrev9(i);
        float mv = mask[base + (size_t)kr * 512 + c] * scale;
        int r = ph(i);
        sR[r][c] *= mv;
        sI[r][c] *= mv;
    }
    fft_dit_inv(sR, sI, twr, twi, c, w);

    for (int it = 0; it < 32; ++it) {
        int i = w + 16 * it;
        bRe[base + (size_t)i * 512 + c] = sR[ph(i)][c];
        bIm[base + (size_t)i * 512 + c] = sI[ph(i)][c];
    }
}

// F4: inverse FFT along W (DIF with conj twiddles -> bitrev out, gathered), real part only.
__global__ __launch_bounds__(256) void k_fft_rows_inv(float* bRe, const float* __restrict__ bIm) {
    __shared__ float sR[512][LSTR], sI[512][LSTR];
    __shared__ float twr[256], twi[256];
    int t = threadIdx.x;
    build_tw(twr, twi, t);
    int co = blockIdx.x >> 5, r0 = (blockIdx.x & 31) << 4;
    size_t base = (size_t)co * HW + (size_t)r0 * 512;

    for (int it = 0; it < 32; ++it) {
        int n = t + 256 * it;
        int rr = n >> 9, j = n & 511;
        sR[ph(j)][rr] = bRe[base + rr * 512 + j];
        sI[ph(j)][rr] = bIm[base + rr * 512 + j];
    }
    int c = t & 15, w = t >> 4;
    fft_dif(sR, sI, twr, twi, c, w, -1.0f);
    for (int it = 0; it < 32; ++it) {
        int n = t + 256 * it;
        int rr = n >> 9, k = n & 511;
        bRe[base + rr * 512 + k] = sR[ph(bitrev9(k))][rr];
    }
}

// ---------------- launch ----------------

extern "C" void kernel_launch(void* const* d_in, const int* in_sizes, int n_in,
                              void* d_out, int out_size, void* d_ws, size_t ws_size,
                              hipStream_t stream) {
    const float* x    = (const float*)d_in[0];
    const float* cw   = (const float*)d_in[1];
    const float* cb   = (const float*)d_in[2];
    const float* mask = (const float*)d_in[3];

    float* outRe = (float*)d_out;                    // y -> Re spectrum -> final out (in place)
    char*  ws    = (char*)d_ws;
    float* bIm         = (float*)ws;                                 // 134,217,728 B
    unsigned short* xb = (unsigned short*)(ws + 134217728);          //  33,554,432 B
    unsigned short* wr = (unsigned short*)(ws + 167772160);          //     147,456 B
    // total ws use: ~160 MB

    k_cvt_x<<<16384, 256, 0, stream>>>((const float4*)x, (ushort4*)xb);
    k_cvt_w<<<288, 256, 0, stream>>>(cw, wr);
    k_conv<<<2048, 256, 0, stream>>>(xb, wr, cb, outRe);
    k_fft_rows_fwd<<<4096, 256, 0, stream>>>(outRe, bIm);
    k_fft_cols<<<4096, 256, 0, stream>>>(outRe, bIm, mask);
    k_fft_rows_inv<<<4096, 256, 0, stream>>>(outRe, bIm);
}

// Round 3
// 996.077 us; speedup vs baseline: 1.2772x; 1.2772x over previous
//
#include <hip/hip_runtime.h>

#define CIN   64
#define COUT  128
#define HH    512
#define WW    512
#define HW    (HH*WW)          // 262144

typedef __attribute__((ext_vector_type(8))) short  short8;   // 8 bf16
typedef __attribute__((ext_vector_type(4))) float  floatx4;

// ---------------- helpers ----------------

__device__ __forceinline__ unsigned short f2bf(float f) {
    unsigned u = __float_as_uint(f);
    u += 0x7fffu + ((u >> 16) & 1u);     // RNE
    return (unsigned short)(u >> 16);
}

// ---------------- conv: implicit GEMM, bf16 MFMA ----------------
// Conversion fp32->bf16 folded into LDS staging (no separate cvt kernels).

__global__ __launch_bounds__(256) void k_conv(
        const float* __restrict__ x,     // fp32 x [ci][h][w]
        const float* __restrict__ cw,    // fp32 conv_w [co][ci][3][3]
        const float* __restrict__ bias,
        float* __restrict__ y)           // fp32 [co][h][w]
{
    __shared__ __align__(16) unsigned short As[3][130][72];  // [dy][wpos][ci]
    __shared__ __align__(16) unsigned short Bs[128][72];     // [co][ci]

    int b  = blockIdx.x;
    int h  = b >> 2;
    int w0 = (b & 3) << 7;
    int t  = threadIdx.x;
    int lane = t & 63, wv = t >> 6;
    int wm = wv & 1, wn = wv >> 1;
    int l15 = lane & 15, quad = lane >> 4;

    for (int idx = t; idx < 3 * 64 * 130; idx += 256) {
        int dy  = idx / (64 * 130);
        int rem = idx - dy * (64 * 130);
        int ci  = rem / 130;
        int p   = rem - ci * 130;
        int hp  = h + dy - 1;
        int wq  = w0 - 1 + p;
        unsigned short v = 0;
        if ((unsigned)hp < 512u && (unsigned)wq < 512u)
            v = f2bf(x[ci * HW + hp * 512 + wq]);
        As[dy][p][ci] = v;
    }

    floatx4 acc[4][4];
#pragma unroll
    for (int mt = 0; mt < 4; ++mt)
#pragma unroll
        for (int nt = 0; nt < 4; ++nt) {
            floatx4 z = {0.f, 0.f, 0.f, 0.f};
            acc[mt][nt] = z;
        }

    for (int tap = 0; tap < 9; ++tap) {
        int dy = tap / 3, dx = tap - dy * 3;
        __syncthreads();
        for (int i = t; i < COUT * CIN; i += 256) {
            Bs[i >> 6][i & 63] = f2bf(cw[i * 9 + tap]);   // i = co*64+ci
        }
        __syncthreads();
#pragma unroll
        for (int kc = 0; kc < 2; ++kc) {
            int c0 = kc * 32 + quad * 8;
            short8 afr[4], bfr[4];
#pragma unroll
            for (int mt = 0; mt < 4; ++mt) {
                int row = wm * 64 + mt * 16 + l15 + dx;
                afr[mt] = *(const short8*)&As[dy][row][c0];
            }
#pragma unroll
            for (int nt = 0; nt < 4; ++nt) {
                int co = wn * 64 + nt * 16 + l15;
                bfr[nt] = *(const short8*)&Bs[co][c0];
            }
#pragma unroll
            for (int mt = 0; mt < 4; ++mt)
#pragma unroll
                for (int nt = 0; nt < 4; ++nt)
                    acc[mt][nt] = __builtin_amdgcn_mfma_f32_16x16x32_bf16(
                        afr[mt], bfr[nt], acc[mt][nt], 0, 0, 0);
        }
    }

#pragma unroll
    for (int nt = 0; nt < 4; ++nt) {
        int co = wn * 64 + nt * 16 + l15;
        float bv = bias[co];
#pragma unroll
        for (int mt = 0; mt < 4; ++mt) {
#pragma unroll
            for (int r = 0; r < 4; ++r) {
                int m = wm * 64 + mt * 16 + quad * 4 + r;
                y[co * HW + h * 512 + w0 + m] = acc[mt][nt][r] + bv;
            }
        }
    }
}

// ---------------- radix-8 register FFT (512 = 8^3) ----------------
// 16 threads per FFT, 32 complex points per thread. Every LDS phase
// transition is separated by __syncthreads() (R2's own-slot no-sync
// write-backs produced warm-run divergence; full barriers fix it).

#define FS 576   // padded index: a + (a>>3), max 511+63 = 574

template<int MODE>
__device__ __forceinline__ int slotf(int c, int a) {
    int m = a + (a >> 3);
    return (MODE == 0) ? c * FS + m   // rows: [c][m]  (lanes vary along a)
                       : m * 16 + c;  // cols: [m][c]  (lanes vary along c)
}

__device__ __forceinline__ float2 cadd(float2 a, float2 b){ return make_float2(a.x+b.x, a.y+b.y); }
__device__ __forceinline__ float2 csub(float2 a, float2 b){ return make_float2(a.x-b.x, a.y-b.y); }

template<int DIR> __device__ __forceinline__ float2 twmul(float2 a, float2 t){
    return (DIR > 0) ? make_float2(a.x*t.x - a.y*t.y, a.x*t.y + a.y*t.x)
                     : make_float2(a.x*t.x + a.y*t.y, a.y*t.x - a.x*t.y);
}
template<int DIR> __device__ __forceinline__ float2 mulJ(float2 a){
    return (DIR > 0) ? make_float2(a.y, -a.x) : make_float2(-a.y, a.x);
}

#define RSQRT2 0.70710678118654752f

template<int DIR> __device__ __forceinline__ void dft8(float2* x){
    float2 a0 = cadd(x[0], x[4]), b0 = csub(x[0], x[4]);
    float2 a1 = cadd(x[1], x[5]), b1 = csub(x[1], x[5]);
    float2 a2 = cadd(x[2], x[6]), b2 = csub(x[2], x[6]);
    float2 a3 = cadd(x[3], x[7]), b3 = csub(x[3], x[7]);
    b1 = (DIR > 0) ? make_float2((b1.x + b1.y)*RSQRT2, (b1.y - b1.x)*RSQRT2)
                   : make_float2((b1.x - b1.y)*RSQRT2, (b1.y + b1.x)*RSQRT2);
    b2 = mulJ<DIR>(b2);
    b3 = (DIR > 0) ? make_float2((b3.y - b3.x)*RSQRT2, -(b3.x + b3.y)*RSQRT2)
                   : make_float2(-(b3.x + b3.y)*RSQRT2, (b3.x - b3.y)*RSQRT2);
    float2 c0 = cadd(a0, a2), d0 = csub(a0, a2);
    float2 c1 = cadd(a1, a3), d1 = mulJ<DIR>(csub(a1, a3));
    x[0] = cadd(c0, c1); x[4] = csub(c0, c1);
    x[2] = cadd(d0, d1); x[6] = csub(d0, d1);
    float2 e0 = cadd(b0, b2), f0 = csub(b0, b2);
    float2 e1 = cadd(b1, b3), f1 = mulJ<DIR>(csub(b1, b3));
    x[1] = cadd(e0, e1); x[5] = csub(e0, e1);
    x[3] = cadd(f0, f1); x[7] = csub(f0, f1);
}

// Forward DIF. Entry: X[b][r] = x[g_b + 64 r], g_b = w + 16 b (natural).
// Exit: X[b][m] = X^(K) at K = (v>>3) + 8*(v&7) + 64*m, v = w + 16 b.
// Caller must __syncthreads() before (tw table / prior buf use).
template<int MODE>
__device__ __forceinline__ void fft512_fwd(float2 X[4][8], float2* buf,
                                           const float2* tw, int w, int c) {
#pragma unroll
    for (int b = 0; b < 4; ++b) {                      // P0 (stride 64)
        dft8<1>(X[b]);
        int g = w + 16*b;
#pragma unroll
        for (int k = 1; k < 8; ++k) X[b][k] = twmul<1>(X[b][k], tw[g*k]);
    }
#pragma unroll
    for (int b = 0; b < 4; ++b) {                      // E0 write: a = k0*64 + g
        int g = w + 16*b;
#pragma unroll
        for (int k = 0; k < 8; ++k) buf[slotf<MODE>(c, k*64 + g)] = X[b][k];
    }
    __syncthreads();
#pragma unroll
    for (int b = 0; b < 4; ++b) {                      // E0 read
        int u = w + 16*b; int bs = (u >> 3)*64 + (u & 7);
#pragma unroll
        for (int g2 = 0; g2 < 8; ++g2) X[b][g2] = buf[slotf<MODE>(c, bs + 8*g2)];
    }
#pragma unroll
    for (int b = 0; b < 4; ++b) {                      // P1 (stride 8)
        dft8<1>(X[b]);
        int g1 = (w + 16*b) & 7;
#pragma unroll
        for (int k = 1; k < 8; ++k) X[b][k] = twmul<1>(X[b][k], tw[8*g1*k]);
    }
    __syncthreads();                                   // E0-read done before E1-write
#pragma unroll
    for (int b = 0; b < 4; ++b) {                      // E1 write
        int u = w + 16*b; int bs = (u >> 3)*64 + (u & 7);
#pragma unroll
        for (int k = 0; k < 8; ++k) buf[slotf<MODE>(c, bs + 8*k)] = X[b][k];
    }
    __syncthreads();
#pragma unroll
    for (int b = 0; b < 4; ++b) {                      // E1 read: a = 8*v + g1
        int v = w + 16*b;
#pragma unroll
        for (int g1 = 0; g1 < 8; ++g1) X[b][g1] = buf[slotf<MODE>(c, 8*v + g1)];
    }
#pragma unroll
    for (int b = 0; b < 4; ++b) dft8<1>(X[b]);         // P2 (no twiddle)
}

// Inverse DIT. Entry: X[b][m] at digit-reversed residency (as fwd exit).
// Exit: X[b][r] = x[g_b + 64 r] (natural order, unscaled).
template<int MODE>
__device__ __forceinline__ void fft512_inv(float2 X[4][8], float2* buf,
                                           const float2* tw, int w, int c) {
#pragma unroll
    for (int b = 0; b < 4; ++b) dft8<-1>(X[b]);        // Q0 (regs only)
    __syncthreads();                                   // protect prior buf reads
#pragma unroll
    for (int b = 0; b < 4; ++b) {                      // E1' write: a = 8*v + g1
        int v = w + 16*b;
#pragma unroll
        for (int g1 = 0; g1 < 8; ++g1) buf[slotf<MODE>(c, 8*v + g1)] = X[b][g1];
    }
    __syncthreads();
#pragma unroll
    for (int b = 0; b < 4; ++b) {                      // E1' read
        int u = w + 16*b; int bs = (u >> 3)*64 + (u & 7);
#pragma unroll
        for (int k = 0; k < 8; ++k) X[b][k] = buf[slotf<MODE>(c, bs + 8*k)];
    }
#pragma unroll
    for (int b = 0; b < 4; ++b) {                      // Q1: conj-tw then idft8
        int g1 = (w + 16*b) & 7;
#pragma unroll
        for (int k = 1; k < 8; ++k) X[b][k] = twmul<-1>(X[b][k], tw[8*g1*k]);
        dft8<-1>(X[b]);
    }
    __syncthreads();                                   // E1'-read done before E0'-write
#pragma unroll
    for (int b = 0; b < 4; ++b) {                      // E0' write
        int u = w + 16*b; int bs = (u >> 3)*64 + (u & 7);
#pragma unroll
        for (int g2 = 0; g2 < 8; ++g2) buf[slotf<MODE>(c, bs + 8*g2)] = X[b][g2];
    }
    __syncthreads();
#pragma unroll
    for (int b = 0; b < 4; ++b) {                      // E0' read: a = k0*64 + g
        int g = w + 16*b;
#pragma unroll
        for (int k = 0; k < 8; ++k) X[b][k] = buf[slotf<MODE>(c, k*64 + g)];
    }
#pragma unroll
    for (int b = 0; b < 4; ++b) {                      // Q2: conj-tw then idft8
        int g = w + 16*b;
#pragma unroll
        for (int k = 1; k < 8; ++k) X[b][k] = twmul<-1>(X[b][k], tw[g*k]);
        dft8<-1>(X[b]);
    }
}

__device__ __forceinline__ void build_tw(float2* tw, int t) {
    const float a0 = -6.283185307179586f / 512.0f;
    float s, c;
    __sincosf(a0 * (float)t, &s, &c);         tw[t]       = make_float2(c, s);
    __sincosf(a0 * (float)(t + 256), &s, &c); tw[t + 256] = make_float2(c, s);
}

// ---- rows forward: real y -> complex spectrum along W, natural order ----
__global__ __launch_bounds__(256) void k_fft_rows_fwd(float* __restrict__ yRe,
                                                      float* __restrict__ yIm) {
    __shared__ float2 buf[16 * FS];
    __shared__ float2 tw[512];
    int t = threadIdx.x;
    build_tw(tw, t);
    int c = t >> 4, w = t & 15;
    int co = blockIdx.x >> 5, r0 = (blockIdx.x & 31) << 4;
    size_t cbase = (size_t)co * HW + (size_t)r0 * 512;
    size_t base  = cbase + (size_t)c * 512;

    float2 X[4][8];
#pragma unroll
    for (int b = 0; b < 4; ++b)
#pragma unroll
        for (int r = 0; r < 8; ++r)
            X[b][r] = make_float2(yRe[base + w + 16*b + 64*r], 0.f);
    __syncthreads();   // tw ready
    fft512_fwd<0>(X, buf, tw, w, c);

    __syncthreads();   // all E1-reads done before reorder writes
#pragma unroll
    for (int b = 0; b < 4; ++b) {
        int v = w + 16*b; int kb = (v >> 3) + 8*(v & 7);
#pragma unroll
        for (int m = 0; m < 8; ++m) buf[slotf<0>(c, kb + 64*m)] = X[b][m];
    }
    __syncthreads();
    for (int it = 0; it < 32; ++it) {
        int n = t + 256*it; int row = n >> 9, col = n & 511;
        float2 v = buf[slotf<0>(row, col)];
        yRe[cbase + (size_t)row*512 + col] = v.x;
        yIm[cbase + (size_t)row*512 + col] = v.y;
    }
}

// ---- cols: fwd FFT along H + mask*scale (digit-rev residency) + inv FFT ----
__global__ __launch_bounds__(256) void k_fft_cols(float* __restrict__ bRe,
                                                  float* __restrict__ bIm,
                                                  const float* __restrict__ mask) {
    __shared__ float2 buf[16 * FS];
    __shared__ float2 tw[512];
    int t = threadIdx.x;
    build_tw(tw, t);
    int c = t & 15, w = t >> 4;
    int co = blockIdx.x >> 5, c0 = (blockIdx.x & 31) << 4;
    size_t base = (size_t)co * HW + (size_t)(c0 + c);

    float2 X[4][8];
#pragma unroll
    for (int b = 0; b < 4; ++b)
#pragma unroll
        for (int r = 0; r < 8; ++r) {
            size_t a = base + (size_t)(w + 16*b + 64*r) * 512;
            X[b][r] = make_float2(bRe[a], bIm[a]);
        }
    __syncthreads();   // tw ready
    fft512_fwd<1>(X, buf, tw, w, c);

    const float scale = 1.0f / 262144.0f;
#pragma unroll
    for (int b = 0; b < 4; ++b) {
        int v = w + 16*b; int kb = (v >> 3) + 8*(v & 7);
#pragma unroll
        for (int m = 0; m < 8; ++m) {
            int kr = kb + 64*m;
            float mv = mask[base + (size_t)kr * 512] * scale;
            X[b][m].x *= mv; X[b][m].y *= mv;
        }
    }
    fft512_inv<1>(X, buf, tw, w, c);
#pragma unroll
    for (int b = 0; b < 4; ++b)
#pragma unroll
        for (int r = 0; r < 8; ++r) {
            size_t a = base + (size_t)(w + 16*b + 64*r) * 512;
            bRe[a] = X[b][r].x;
            bIm[a] = X[b][r].y;
        }
}

// ---- rows inverse: natural spectrum -> real output along W ----
__global__ __launch_bounds__(256) void k_fft_rows_inv(float* __restrict__ bRe,
                                                      const float* __restrict__ bIm) {
    __shared__ float2 buf[16 * FS];
    __shared__ float2 tw[512];
    int t = threadIdx.x;
    build_tw(tw, t);
    int c = t >> 4, w = t & 15;
    int co = blockIdx.x >> 5, r0 = (blockIdx.x & 31) << 4;
    size_t cbase = (size_t)co * HW + (size_t)r0 * 512;

    for (int it = 0; it < 32; ++it) {                 // flat coalesced stage-in
        int n = t + 256*it; int row = n >> 9, col = n & 511;
        size_t a = cbase + (size_t)row*512 + col;
        buf[slotf<0>(row, col)] = make_float2(bRe[a], bIm[a]);
    }
    __syncthreads();

    float2 X[4][8];
#pragma unroll
    for (int b = 0; b < 4; ++b) {                     // gather digit-rev residency
        int v = w + 16*b; int kb = (v >> 3) + 8*(v & 7);
#pragma unroll
        for (int m = 0; m < 8; ++m) X[b][m] = buf[slotf<0>(c, kb + 64*m)];
    }
    fft512_inv<0>(X, buf, tw, w, c);

    size_t base = cbase + (size_t)c * 512;
#pragma unroll
    for (int b = 0; b < 4; ++b)
#pragma unroll
        for (int r = 0; r < 8; ++r)
            bRe[base + w + 16*b + 64*r] = X[b][r].x;
}

// ---------------- launch ----------------

extern "C" void kernel_launch(void* const* d_in, const int* in_sizes, int n_in,
                              void* d_out, int out_size, void* d_ws, size_t ws_size,
                              hipStream_t stream) {
    const float* x    = (const float*)d_in[0];
    const float* cw   = (const float*)d_in[1];
    const float* cb   = (const float*)d_in[2];
    const float* mask = (const float*)d_in[3];

    float* outRe = (float*)d_out;        // y -> Re spectrum -> final out (in place)
    float* bIm   = (float*)d_ws;         // 134,217,728 B (only ws use)

    k_conv<<<2048, 256, 0, stream>>>(x, cw, cb, outRe);
    k_fft_rows_fwd<<<4096, 256, 0, stream>>>(outRe, bIm);
    k_fft_cols<<<4096, 256, 0, stream>>>(outRe, bIm, mask);
    k_fft_rows_inv<<<4096, 256, 0, stream>>>(outRe, bIm);
}